// Round 1
// baseline (1207.266 us; speedup 1.0000x reference)
//
#include <hip/hip_runtime.h>
#include <cstddef>
#include <cstdint>

#define Tn 512
#define Bn 512
#define Hn 64

__device__ __forceinline__ float rlane(float v, int lane) {
    return __uint_as_float((unsigned)__builtin_amdgcn_readlane((int)__float_as_uint(v), lane));
}
__device__ __forceinline__ float sigm(float x) { return 1.0f / (1.0f + __expf(-x)); }
// tanh(x) = 1 - 2/(1+e^{2x}); inf-safe at both ends
__device__ __forceinline__ float tanhf_(float x) { return 1.0f - 2.0f / (1.0f + __expf(2.0f * x)); }

// ---------------------------------------------------------------------------
// Layer 0 (IN=1), both directions. One wave per (batch, dir) task.
// Lane j owns hidden unit j: its 4 gate rows (i,f,g,o) of w_hh live in VGPRs
// (4x64 floats). h broadcast via v_readlane (VALU), amortized over 4 FMAs.
// No barriers, no LDS except the staged x row.
// ---------------------------------------------------------------------------
__global__ __launch_bounds__(64, 1) void k_lstm_l0(
    const float* __restrict__ x,
    const float* __restrict__ wih_f, const float* __restrict__ whh_f,
    const float* __restrict__ bih_f, const float* __restrict__ bhh_f,
    const float* __restrict__ wih_r, const float* __restrict__ whh_r,
    const float* __restrict__ bih_r, const float* __restrict__ bhh_r,
    float* __restrict__ h0)
{
    const int task = blockIdx.x;
    const int b = task >> 1;
    const int dir = task & 1;
    const int j = threadIdx.x;  // 0..63

    const float* __restrict__ wih = dir ? wih_r : wih_f;
    const float* __restrict__ whh = dir ? whh_r : whh_f;
    const float* __restrict__ bih = dir ? bih_r : bih_f;
    const float* __restrict__ bhh = dir ? bhh_r : bhh_f;

    // stage this batch row of x (T scalars) into LDS
    __shared__ float xs[Tn];
    #pragma unroll
    for (int i = 0; i < Tn / 64; ++i) xs[i * 64 + j] = x[b * Tn + i * 64 + j];
    __syncthreads();

    // per-lane weights: w[g][k] = w_hh[g*64+j][k]
    float w[4][64];
    float wx[4], bias[4];
    #pragma unroll
    for (int g = 0; g < 4; ++g) {
        const int r = g * 64 + j;
        wx[g] = wih[r];                 // IN == 1
        bias[g] = bih[r] + bhh[r];
        #pragma unroll
        for (int k4 = 0; k4 < 16; ++k4) {
            const float4 v = *reinterpret_cast<const float4*>(&whh[r * 64 + k4 * 4]);
            w[g][k4 * 4 + 0] = v.x; w[g][k4 * 4 + 1] = v.y;
            w[g][k4 * 4 + 2] = v.z; w[g][k4 * 4 + 3] = v.w;
        }
    }

    float h = 0.0f, c = 0.0f;
    float* __restrict__ outp = h0 + (size_t)b * Tn * 128 + dir * 64 + j;

    for (int s = 0; s < Tn; ++s) {
        const int t = dir ? (Tn - 1 - s) : s;   // bwd scan: process T-1..0, store at t
        const float xt = xs[t];
        float a0 = fmaf(xt, wx[0], bias[0]);
        float a1 = fmaf(xt, wx[1], bias[1]);
        float a2 = fmaf(xt, wx[2], bias[2]);
        float a3 = fmaf(xt, wx[3], bias[3]);
        #pragma unroll
        for (int k = 0; k < 64; ++k) {
            const float hk = rlane(h, k);
            a0 = fmaf(hk, w[0][k], a0);
            a1 = fmaf(hk, w[1][k], a1);
            a2 = fmaf(hk, w[2][k], a2);
            a3 = fmaf(hk, w[3][k], a3);
        }
        c = sigm(a1) * c + sigm(a0) * tanhf_(a2);
        h = sigm(a3) * tanhf_(c);
        outp[(size_t)t * 128] = h;
    }
}

// ---------------------------------------------------------------------------
// Layer 1 forward scan, input GEMM fused (K = 128 input + 64 recurrent = 192).
// One block (4 waves) per batch element. K is split 48 per wave; partial gate
// sums are reduced through double-buffered LDS (one barrier per step).
// Only the final h is needed (for the FC on h1[:, -1]).
// ---------------------------------------------------------------------------
__global__ __launch_bounds__(256, 2) void k_lstm_l1f(
    const float* __restrict__ h0,
    const float* __restrict__ wih, const float* __restrict__ whh,
    const float* __restrict__ bih, const float* __restrict__ bhh,
    float* __restrict__ h1last)
{
    const int b = blockIdx.x;
    const int tid = threadIdx.x;
    const int wv = tid >> 6;    // wave 0..3 -> k range [48*wv, 48*wv+48)
    const int j = tid & 63;     // hidden unit

    float bias[4];
    #pragma unroll
    for (int g = 0; g < 4; ++g) {
        const int r = g * 64 + j;
        bias[g] = bih[r] + bhh[r];
    }

    // wt[g][kk]: weight for K-index k = 48*wv + kk.
    // k in [0,128): wih[r*128+k]; k in [128,192): whh[r*64 + k-128]
    float wt[4][48];
    if (wv == 0) {
        #pragma unroll
        for (int g = 0; g < 4; ++g) {
            const int r = g * 64 + j;
            #pragma unroll
            for (int kk = 0; kk < 48; ++kk) wt[g][kk] = wih[r * 128 + kk];
        }
    } else if (wv == 1) {
        #pragma unroll
        for (int g = 0; g < 4; ++g) {
            const int r = g * 64 + j;
            #pragma unroll
            for (int kk = 0; kk < 48; ++kk) wt[g][kk] = wih[r * 128 + 48 + kk];
        }
    } else if (wv == 2) {
        #pragma unroll
        for (int g = 0; g < 4; ++g) {
            const int r = g * 64 + j;
            #pragma unroll
            for (int kk = 0; kk < 48; ++kk)
                wt[g][kk] = (kk < 32) ? wih[r * 128 + 96 + kk] : whh[r * 64 + (kk - 32)];
        }
    } else {
        #pragma unroll
        for (int g = 0; g < 4; ++g) {
            const int r = g * 64 + j;
            #pragma unroll
            for (int kk = 0; kk < 48; ++kk) wt[g][kk] = whh[r * 64 + 16 + kk];
        }
    }

    const float* __restrict__ xrow = h0 + (size_t)b * Tn * 128;
    float x1a = xrow[j];        // x1[lane]      (fwd half of layer-0 out, t=0)
    float x1b = xrow[64 + j];   // x1[64+lane]   (bwd half)
    float h = 0.0f, c = 0.0f;

    __shared__ float part[2][4][64][4];  // [buf][wave][unit][gate], 8 KB

    for (int t = 0; t < Tn; ++t) {
        // prefetch next step's x1 (hidden under the FMA loop)
        float nx1a = 0.0f, nx1b = 0.0f;
        if (t + 1 < Tn) {
            nx1a = xrow[(t + 1) * 128 + j];
            nx1b = xrow[(t + 1) * 128 + 64 + j];
        }
        float a0 = 0.0f, a1 = 0.0f, a2 = 0.0f, a3 = 0.0f;
        if (wv == 0) {          // k = kk in [0,48): x1a lanes 0..47
            #pragma unroll
            for (int kk = 0; kk < 48; ++kk) {
                const float v = rlane(x1a, kk);
                a0 = fmaf(v, wt[0][kk], a0); a1 = fmaf(v, wt[1][kk], a1);
                a2 = fmaf(v, wt[2][kk], a2); a3 = fmaf(v, wt[3][kk], a3);
            }
        } else if (wv == 1) {   // k in [48,96): x1a 48..63 then x1b 0..31
            #pragma unroll
            for (int kk = 0; kk < 48; ++kk) {
                const float v = (kk < 16) ? rlane(x1a, 48 + kk) : rlane(x1b, kk - 16);
                a0 = fmaf(v, wt[0][kk], a0); a1 = fmaf(v, wt[1][kk], a1);
                a2 = fmaf(v, wt[2][kk], a2); a3 = fmaf(v, wt[3][kk], a3);
            }
        } else if (wv == 2) {   // k in [96,144): x1b 32..63 then h 0..15
            #pragma unroll
            for (int kk = 0; kk < 48; ++kk) {
                const float v = (kk < 32) ? rlane(x1b, 32 + kk) : rlane(h, kk - 32);
                a0 = fmaf(v, wt[0][kk], a0); a1 = fmaf(v, wt[1][kk], a1);
                a2 = fmaf(v, wt[2][kk], a2); a3 = fmaf(v, wt[3][kk], a3);
            }
        } else {                // k in [144,192): h 16..63
            #pragma unroll
            for (int kk = 0; kk < 48; ++kk) {
                const float v = rlane(h, 16 + kk);
                a0 = fmaf(v, wt[0][kk], a0); a1 = fmaf(v, wt[1][kk], a1);
                a2 = fmaf(v, wt[2][kk], a2); a3 = fmaf(v, wt[3][kk], a3);
            }
        }
        *reinterpret_cast<float4*>(&part[t & 1][wv][j][0]) = make_float4(a0, a1, a2, a3);
        __syncthreads();
        const float4 p0 = *reinterpret_cast<const float4*>(&part[t & 1][0][j][0]);
        const float4 p1 = *reinterpret_cast<const float4*>(&part[t & 1][1][j][0]);
        const float4 p2 = *reinterpret_cast<const float4*>(&part[t & 1][2][j][0]);
        const float4 p3 = *reinterpret_cast<const float4*>(&part[t & 1][3][j][0]);
        const float gi = bias[0] + p0.x + p1.x + p2.x + p3.x;
        const float gf = bias[1] + p0.y + p1.y + p2.y + p3.y;
        const float gg = bias[2] + p0.z + p1.z + p2.z + p3.z;
        const float go = bias[3] + p0.w + p1.w + p2.w + p3.w;
        // every wave updates its own (identical) copy of c,h -> deterministic
        c = sigm(gf) * c + sigm(gi) * tanhf_(gg);
        h = sigm(go) * tanhf_(c);
        x1a = nx1a; x1b = nx1b;
    }
    if (tid < 64) h1last[(size_t)b * 64 + j] = h;
}

// ---------------------------------------------------------------------------
// Layer-1 backward direction collapses to ONE step at t=T-1 (zero init state),
// then the final FC: out[b] = dot(h1_fwd_last, fcw[0:64]) + dot(h1_bwd_last,
// fcw[64:128]) + fcb. One wave per batch element.
// ---------------------------------------------------------------------------
__global__ __launch_bounds__(64, 1) void k_l1r_fc(
    const float* __restrict__ h0,
    const float* __restrict__ wihr,
    const float* __restrict__ bihr, const float* __restrict__ bhhr,
    const float* __restrict__ h1last,
    const float* __restrict__ fcw, const float* __restrict__ fcb,
    float* __restrict__ out)
{
    const int b = blockIdx.x;
    const int j = threadIdx.x;
    const float* __restrict__ xrow = h0 + ((size_t)b * Tn + (Tn - 1)) * 128;
    const float x1a = xrow[j];
    const float x1b = xrow[64 + j];
    float acc[4];
    #pragma unroll
    for (int g = 0; g < 4; ++g) {
        const int r = g * 64 + j;
        float a = bihr[r] + bhhr[r];
        const float* __restrict__ wr = wihr + (size_t)r * 128;
        #pragma unroll
        for (int d4 = 0; d4 < 16; ++d4) {
            const float4 w4 = *reinterpret_cast<const float4*>(&wr[d4 * 4]);
            a = fmaf(rlane(x1a, d4 * 4 + 0), w4.x, a);
            a = fmaf(rlane(x1a, d4 * 4 + 1), w4.y, a);
            a = fmaf(rlane(x1a, d4 * 4 + 2), w4.z, a);
            a = fmaf(rlane(x1a, d4 * 4 + 3), w4.w, a);
        }
        #pragma unroll
        for (int d4 = 0; d4 < 16; ++d4) {
            const float4 w4 = *reinterpret_cast<const float4*>(&wr[64 + d4 * 4]);
            a = fmaf(rlane(x1b, d4 * 4 + 0), w4.x, a);
            a = fmaf(rlane(x1b, d4 * 4 + 1), w4.y, a);
            a = fmaf(rlane(x1b, d4 * 4 + 2), w4.z, a);
            a = fmaf(rlane(x1b, d4 * 4 + 3), w4.w, a);
        }
        acc[g] = a;
    }
    // h_prev = c_prev = 0: no recurrent term; c = sig(i)*tanh(g)
    const float cr = sigm(acc[0]) * tanhf_(acc[2]);
    const float hr = sigm(acc[3]) * tanhf_(cr);
    float v = h1last[(size_t)b * 64 + j] * fcw[j] + hr * fcw[64 + j];
    #pragma unroll
    for (int off = 32; off > 0; off >>= 1) v += __shfl_xor(v, off, 64);
    if (j == 0) out[b] = v + fcb[0];
}

// ---------------------------------------------------------------------------
extern "C" void kernel_launch(void* const* d_in, const int* in_sizes, int n_in,
                              void* d_out, int out_size, void* d_ws, size_t ws_size,
                              hipStream_t stream)
{
    const float* x       = (const float*)d_in[0];
    const float* wih_l0  = (const float*)d_in[1];
    const float* whh_l0  = (const float*)d_in[2];
    const float* bih_l0  = (const float*)d_in[3];
    const float* bhh_l0  = (const float*)d_in[4];
    const float* wih_l0r = (const float*)d_in[5];
    const float* whh_l0r = (const float*)d_in[6];
    const float* bih_l0r = (const float*)d_in[7];
    const float* bhh_l0r = (const float*)d_in[8];
    const float* wih_l1  = (const float*)d_in[9];
    const float* whh_l1  = (const float*)d_in[10];
    const float* bih_l1  = (const float*)d_in[11];
    const float* bhh_l1  = (const float*)d_in[12];
    const float* wih_l1r = (const float*)d_in[13];
    const float* whh_l1r = (const float*)d_in[14];
    const float* bih_l1r = (const float*)d_in[15];
    const float* bhh_l1r = (const float*)d_in[16];
    const float* fcw     = (const float*)d_in[17];
    const float* fcb     = (const float*)d_in[18];
    (void)whh_l1r; (void)in_sizes; (void)n_in; (void)out_size;

    // ws layout: h0 [512][512][128] f32 (134.2 MB) + h1last [512][64] f32
    float* h0     = (float*)d_ws;
    float* h1last = h0 + (size_t)Bn * Tn * 128;
    (void)ws_size;  // requires ~134.4 MB

    k_lstm_l0<<<dim3(Bn * 2), dim3(64), 0, stream>>>(
        x, wih_l0, whh_l0, bih_l0, bhh_l0,
        wih_l0r, whh_l0r, bih_l0r, bhh_l0r, h0);
    k_lstm_l1f<<<dim3(Bn), dim3(256), 0, stream>>>(
        h0, wih_l1, whh_l1, bih_l1, bhh_l1, h1last);
    k_l1r_fc<<<dim3(Bn), dim3(64), 0, stream>>>(
        h0, wih_l1r, bih_l1r, bhh_l1r, h1last, fcw, fcb, (float*)d_out);
}